// Round 5
// baseline (278.617 us; speedup 1.0000x reference)
//
#include <hip/hip_runtime.h>
#include <math.h>

namespace {

constexpr int B_ = 4;
constexpr int N_ = 512;
constexpr int D_ = 256;
constexpr int L_ = 128;
constexpr int TI = 4;   // i-rows per block in dist kernel
constexpr int REP = 16; // instrumentation: repeat main loops to surface in rocprof

// xs[b][l][n] = a[l] * sum_d x[b][n][d] * W[l][d]   (transposed, a-scaled)
__global__ __launch_bounds__(128) void proj_kernel(
    const float* __restrict__ x, const float* __restrict__ W,
    const float* __restrict__ a, float* __restrict__ xs) {
  const int tid = threadIdx.x;
  const int b = blockIdx.z;
  const int n = blockIdx.y * 128 + tid;
  const int l0 = blockIdx.x * 4;
  const float4* __restrict__ x4 =
      reinterpret_cast<const float4*>(x + (size_t)(b * N_ + n) * D_);
  const float4* __restrict__ W4 = reinterpret_cast<const float4*>(W);
  float acc0, acc1, acc2, acc3;
  for (int rep = 0; rep < REP; ++rep) {
    acc0 = acc1 = acc2 = acc3 = 0.f;
#pragma unroll 4
    for (int d4 = 0; d4 < D_ / 4; ++d4) {
      const float4 xv = x4[d4];
      const float4 w0 = W4[(l0 + 0) * (D_ / 4) + d4];
      const float4 w1 = W4[(l0 + 1) * (D_ / 4) + d4];
      const float4 w2 = W4[(l0 + 2) * (D_ / 4) + d4];
      const float4 w3 = W4[(l0 + 3) * (D_ / 4) + d4];
      acc0 += xv.x * w0.x + xv.y * w0.y + xv.z * w0.z + xv.w * w0.w;
      acc1 += xv.x * w1.x + xv.y * w1.y + xv.z * w1.z + xv.w * w1.w;
      acc2 += xv.x * w2.x + xv.y * w2.y + xv.z * w2.z + xv.w * w2.w;
      acc3 += xv.x * w3.x + xv.y * w3.y + xv.z * w3.z + xv.w * w3.w;
    }
    // keep each rep's result live without storing (anti-DCE/hoist)
    asm volatile("" ::"v"(acc0), "v"(acc1), "v"(acc2), "v"(acc3));
  }
  float* o = xs + (size_t)(b * L_ + l0) * N_ + n;
  o[0 * N_] = acc0 * a[l0 + 0];
  o[1 * N_] = acc1 * a[l0 + 1];
  o[2 * N_] = acc2 * a[l0 + 2];
  o[3 * N_] = acc3 * a[l0 + 3];
}

// Fused: L1 distance (a pre-folded) + mask, leaky-relu, row softmax with adj.
// Block = (b, i-tile of TI rows), 512 threads = one j column each.
__global__ __launch_bounds__(512) void dist_softmax_kernel(
    const float* __restrict__ xs, const float* __restrict__ adj,
    const int* __restrict__ box_num, const float* __restrict__ a,
    float* __restrict__ out) {
  const int t = threadIdx.x;
  const int j = t;
  const int i0 = blockIdx.x * TI;
  const int b = blockIdx.y;
  const int bn = box_num[b];
  const float* __restrict__ xs_b = xs + (size_t)b * L_ * N_;

  __shared__ float xi_l[L_ * TI];  // [l][r], 2 KB, read as broadcast float4
  __shared__ float red[8][TI];
  __shared__ float sa_l[2];
  __shared__ float rmax_s[TI];
  __shared__ float rsinv_s[TI];

  // stage i-rows: thread t -> (l = t>>2, r = t&3)
  xi_l[t] = xs_b[(t >> 2) * N_ + i0 + (t & 3)];

  // sum(a) prologue
  {
    float sa = (t < L_) ? a[t] : 0.f;
#pragma unroll
    for (int off = 1; off < 64; off <<= 1) sa += __shfl_xor(sa, off);
    if (t == 0) sa_l[0] = sa;
    if (t == 64) sa_l[1] = sa;
  }
  __syncthreads();
  const float sum_a = sa_l[0] + sa_l[1];

  float acc[TI];
  const float4* __restrict__ xi4 = reinterpret_cast<const float4*>(xi_l);
  for (int rep = 0; rep < REP; ++rep) {
#pragma unroll
    for (int r = 0; r < TI; ++r) acc[r] = 0.f;
#pragma unroll 4
    for (int l = 0; l < L_; ++l) {
      const float xj = xs_b[l * N_ + j];  // coalesced 4B/lane
      const float4 xi = xi4[l];           // ds_read_b128, broadcast
      acc[0] += fabsf(xi.x - xj);
      acc[1] += fabsf(xi.y - xj);
      acc[2] += fabsf(xi.z - xj);
      acc[3] += fabsf(xi.w - xj);
    }
    asm volatile("" ::"v"(acc[0]), "v"(acc[1]), "v"(acc[2]), "v"(acc[3]));
  }

  const bool vj = j < bn;
  float val[TI];
#pragma unroll
  for (int r = 0; r < TI; ++r) {
    const bool vi = (i0 + r) < bn;
    const float d = acc[r] - ((vi && vj) ? 0.f : sum_a);  // + mask*sum(a)
    val[r] = d >= 0.f ? d : 0.01f * d;                    // leaky_relu
  }

  const int lane = t & 63;
  const int wid = t >> 6;

  // ---- row max over 512 j ----
  {
    float wm[TI];
#pragma unroll
    for (int r = 0; r < TI; ++r) {
      float m = val[r];
#pragma unroll
      for (int off = 1; off < 64; off <<= 1) m = fmaxf(m, __shfl_xor(m, off));
      wm[r] = m;
    }
    if (lane == 0) {
#pragma unroll
      for (int r = 0; r < TI; ++r) red[wid][r] = wm[r];
    }
  }
  __syncthreads();
  if (t < TI) {
    float m = red[0][t];
#pragma unroll
    for (int w = 1; w < 8; ++w) m = fmaxf(m, red[w][t]);
    rmax_s[t] = m;
  }
  __syncthreads();

  float e[TI];
  const float* __restrict__ adjp = adj + ((size_t)(b * N_ + i0)) * N_ + j;
#pragma unroll
  for (int r = 0; r < TI; ++r) {
    e[r] = adjp[(size_t)r * N_] * expf(val[r] - rmax_s[r]);
  }

  // ---- row sum over 512 j ----
  {
    float wsum[TI];
#pragma unroll
    for (int r = 0; r < TI; ++r) {
      float s = e[r];
#pragma unroll
      for (int off = 1; off < 64; off <<= 1) s += __shfl_xor(s, off);
      wsum[r] = s;
    }
    if (lane == 0) {
#pragma unroll
      for (int r = 0; r < TI; ++r) red[wid][r] = wsum[r];
    }
  }
  __syncthreads();
  if (t < TI) {
    float s = red[0][t];
#pragma unroll
    for (int w = 1; w < 8; ++w) s += red[w][t];
    rsinv_s[t] = 1.0f / s;
  }
  __syncthreads();

  float* __restrict__ op = out + ((size_t)(b * N_ + i0)) * N_ + j;
#pragma unroll
  for (int r = 0; r < TI; ++r) {
    op[(size_t)r * N_] = e[r] * rsinv_s[r] + 1e-10f;
  }
}

}  // namespace

extern "C" void kernel_launch(void* const* d_in, const int* in_sizes, int n_in,
                              void* d_out, int out_size, void* d_ws,
                              size_t ws_size, hipStream_t stream) {
  const float* x = (const float*)d_in[0];    // (B,N,D) f32
  const float* adj = (const float*)d_in[1];  // (B,N,N) f32
  const int* box_num = (const int*)d_in[2];  // (B,1) int32
  const float* W = (const float*)d_in[3];    // (L,D) f32
  const float* a = (const float*)d_in[4];    // (L,) f32
  float* out = (float*)d_out;                // (B,N,N) f32
  float* xs = (float*)d_ws;                  // B*L*N floats = 1 MB scratch

  dim3 g1(L_ / 4, N_ / 128, B_);
  proj_kernel<<<g1, 128, 0, stream>>>(x, W, a, xs);

  dim3 g2(N_ / TI, B_);
  dist_softmax_kernel<<<g2, 512, 0, stream>>>(xs, adj, box_num, a, out);
}

// Round 6
// 31.272 us; speedup vs baseline: 8.9095x; 8.9095x over previous
//
#include <hip/hip_runtime.h>
#include <math.h>

namespace {

constexpr int B_ = 4;
constexpr int N_ = 512;
constexpr int D_ = 256;
constexpr int L_ = 128;
constexpr int TI = 8;  // i-rows per block in dist kernel

// xs[b][l][n] = a[l] * sum_d x[b][n][d] * W[l][d]
// Block: 256 thr = 64 n (lane) x 4 l-groups (wave-uniform) x 4 l each.
// x staged in LDS (coalesced global reads, conflict-free LDS reads),
// W via wave-uniform reads -> s_load (scalar pipe).
__global__ __launch_bounds__(256) void proj_kernel(
    const float* __restrict__ x, const float* __restrict__ W,
    const float* __restrict__ a, float* __restrict__ xs) {
  const int t = threadIdx.x;
  const int b = blockIdx.z;
  const int n0 = blockIdx.y * 64;
  const int l0 = blockIdx.x * 16;

  __shared__ float xl[64 * 129];  // 33 KB; row stride 129 -> bank (n+d)%32

  const int n = t & 63;
  const int lg = __builtin_amdgcn_readfirstlane(t >> 6);  // wave-uniform 0..3
  const int lbase = l0 + lg * 4;
  const float4* __restrict__ W4 = reinterpret_cast<const float4*>(W);
  const float* __restrict__ xrow = xl + n * 129;

  float acc[4] = {0.f, 0.f, 0.f, 0.f};

#pragma unroll
  for (int half = 0; half < 2; ++half) {
    if (half) __syncthreads();  // protect LDS reuse
    // stage x[b][n0..n0+64][half*128 .. +128] -> LDS, coalesced float4 reads
    {
      const float4* __restrict__ xsrc = reinterpret_cast<const float4*>(
          x + ((size_t)(b * N_ + n0)) * D_ + half * 128);
#pragma unroll
      for (int k = 0; k < 8; ++k) {
        const int idx = t + k * 256;        // 0..2047
        const int sn = idx >> 5;            // local n
        const int sq = idx & 31;            // quad within 128-chunk
        // global row stride D/4=64 float4; we read quads 0..31 of this half
        const float4 v = xsrc[(size_t)sn * 64 + sq];
        float* dst = xl + sn * 129 + sq * 4;
        dst[0] = v.x; dst[1] = v.y; dst[2] = v.z; dst[3] = v.w;
      }
    }
    __syncthreads();

#pragma unroll 4
    for (int d4 = 0; d4 < 32; ++d4) {
      const float x0 = xrow[d4 * 4 + 0];
      const float x1 = xrow[d4 * 4 + 1];
      const float x2 = xrow[d4 * 4 + 2];
      const float x3 = xrow[d4 * 4 + 3];
#pragma unroll
      for (int k = 0; k < 4; ++k) {
        // address uniform per wave -> s_load_dwordx4
        const float4 w = W4[(size_t)(lbase + k) * 64 + half * 32 + d4];
        acc[k] += x0 * w.x + x1 * w.y + x2 * w.z + x3 * w.w;
      }
    }
  }

#pragma unroll
  for (int k = 0; k < 4; ++k) {
    const int l = lbase + k;
    xs[((size_t)(b * L_ + l)) * N_ + n0 + n] = acc[k] * a[l];  // coalesced
  }
}

// Fused: L1 distance (a pre-folded) + mask, leaky-relu, row softmax with adj.
// Block = (i-tile of TI=8 rows, b), 512 threads = one j column each.
// xi via uniform loads (-> s_load, scalar pipe); xj coalesced dword.
// NO LDS in the main loop.
__global__ __launch_bounds__(512) void dist_softmax_kernel(
    const float* __restrict__ xs, const float* __restrict__ adj,
    const int* __restrict__ box_num, const float* __restrict__ a,
    float* __restrict__ out) {
  const int t = threadIdx.x;
  const int j = t;
  const int i0 = blockIdx.x * TI;
  const int b = blockIdx.y;
  const int bn = box_num[b];
  const float* __restrict__ xs_b = xs + (size_t)b * L_ * N_;

  __shared__ float red[8][TI];
  __shared__ float sa_l[2];
  __shared__ float rmax_s[TI];
  __shared__ float rsinv_s[TI];

  // sum(a) prologue
  {
    float sa = (t < L_) ? a[t] : 0.f;
#pragma unroll
    for (int off = 1; off < 64; off <<= 1) sa += __shfl_xor(sa, off);
    if (t == 0) sa_l[0] = sa;
    if (t == 64) sa_l[1] = sa;
  }
  __syncthreads();
  const float sum_a = sa_l[0] + sa_l[1];

  float acc[TI];
#pragma unroll
  for (int r = 0; r < TI; ++r) acc[r] = 0.f;

  const float* __restrict__ pj = xs_b + j;
#pragma unroll 4
  for (int l = 0; l < L_; ++l) {
    const float xj = pj[(size_t)l * N_];               // coalesced 4B/lane
    const float* __restrict__ xi = xs_b + (size_t)l * N_ + i0;  // uniform
#pragma unroll
    for (int r = 0; r < TI; ++r) {
      acc[r] += fabsf(xi[r] - xj);  // v_sub(s,v) + v_add(abs)
    }
  }

  const bool vj = j < bn;
  float val[TI];
#pragma unroll
  for (int r = 0; r < TI; ++r) {
    const bool vi = (i0 + r) < bn;
    const float d = acc[r] - ((vi && vj) ? 0.f : sum_a);  // + mask*sum(a)
    val[r] = d >= 0.f ? d : 0.01f * d;                    // leaky_relu
  }

  const int lane = t & 63;
  const int wid = t >> 6;

  // ---- row max over 512 j ----
  {
    float wm[TI];
#pragma unroll
    for (int r = 0; r < TI; ++r) {
      float m = val[r];
#pragma unroll
      for (int off = 1; off < 64; off <<= 1) m = fmaxf(m, __shfl_xor(m, off));
      wm[r] = m;
    }
    if (lane == 0) {
#pragma unroll
      for (int r = 0; r < TI; ++r) red[wid][r] = wm[r];
    }
  }
  __syncthreads();
  if (t < TI) {
    float m = red[0][t];
#pragma unroll
    for (int w = 1; w < 8; ++w) m = fmaxf(m, red[w][t]);
    rmax_s[t] = m;
  }
  __syncthreads();

  float e[TI];
  const float* __restrict__ adjp = adj + ((size_t)(b * N_ + i0)) * N_ + j;
#pragma unroll
  for (int r = 0; r < TI; ++r) {
    e[r] = adjp[(size_t)r * N_] * __expf(val[r] - rmax_s[r]);
  }

  // ---- row sum over 512 j ----
  {
    float wsum[TI];
#pragma unroll
    for (int r = 0; r < TI; ++r) {
      float s = e[r];
#pragma unroll
      for (int off = 1; off < 64; off <<= 1) s += __shfl_xor(s, off);
      wsum[r] = s;
    }
    if (lane == 0) {
#pragma unroll
      for (int r = 0; r < TI; ++r) red[wid][r] = wsum[r];
    }
  }
  __syncthreads();
  if (t < TI) {
    float s = red[0][t];
#pragma unroll
    for (int w = 1; w < 8; ++w) s += red[w][t];
    rsinv_s[t] = 1.0f / s;
  }
  __syncthreads();

  float* __restrict__ op = out + ((size_t)(b * N_ + i0)) * N_ + j;
#pragma unroll
  for (int r = 0; r < TI; ++r) {
    op[(size_t)r * N_] = e[r] * rsinv_s[r] + 1e-10f;
  }
}

}  // namespace

extern "C" void kernel_launch(void* const* d_in, const int* in_sizes, int n_in,
                              void* d_out, int out_size, void* d_ws,
                              size_t ws_size, hipStream_t stream) {
  const float* x = (const float*)d_in[0];    // (B,N,D) f32
  const float* adj = (const float*)d_in[1];  // (B,N,N) f32
  const int* box_num = (const int*)d_in[2];  // (B,1) int32
  const float* W = (const float*)d_in[3];    // (L,D) f32
  const float* a = (const float*)d_in[4];    // (L,) f32
  float* out = (float*)d_out;                // (B,N,N) f32
  float* xs = (float*)d_ws;                  // B*L*N floats = 1 MB scratch

  dim3 g1(L_ / 16, N_ / 64, B_);
  proj_kernel<<<g1, 256, 0, stream>>>(x, W, a, xs);

  dim3 g2(N_ / TI, B_);
  dist_softmax_kernel<<<g2, 512, 0, stream>>>(xs, adj, box_num, a, out);
}

// Round 7
// 30.331 us; speedup vs baseline: 9.1858x; 1.0310x over previous
//
#include <hip/hip_runtime.h>
#include <math.h>

namespace {

constexpr int B_ = 4;
constexpr int N_ = 512;
constexpr int D_ = 256;
constexpr int L_ = 128;
constexpr int TI = 8;  // i-rows per dist block (two 512-thread groups split l)

// xs[b][l][n] = a[l] * sum_d x[b][n][d] * W[l][d]
// Block: 256 thr = 64 n x 4 l-groups x 4 l. W-tile AND x-tile staged in LDS:
// all compute reads are LDS (broadcast for W, conflict-free b128 for x).
__global__ __launch_bounds__(256) void proj_kernel(
    const float* __restrict__ x, const float* __restrict__ W,
    const float* __restrict__ a, float* __restrict__ xs) {
  const int t = threadIdx.x;
  const int b = blockIdx.z;
  const int n0 = blockIdx.y * 64;
  const int l0 = blockIdx.x * 16;

  __shared__ float wl_s[16 * 256];  // 16 KB W tile
  __shared__ float xl[64 * 129];    // 33 KB x half-tile, pad 129

  const int n = t & 63;
  const int lg = t >> 6;  // 0..3, wave-uniform
  const float* __restrict__ xrow = xl + n * 129;

  // stage W tile (16 l x 256 d), coalesced float4
  {
    const float4* __restrict__ Wsrc =
        reinterpret_cast<const float4*>(W + (size_t)l0 * D_);
    float4* wdst = reinterpret_cast<float4*>(wl_s);
#pragma unroll
    for (int k = 0; k < 4; ++k) wdst[t + k * 256] = Wsrc[t + k * 256];
  }

  float acc[4] = {0.f, 0.f, 0.f, 0.f};

#pragma unroll
  for (int half = 0; half < 2; ++half) {
    __syncthreads();  // W ready (half 0) / protect x reuse (half 1)
    // stage x[b][n0..+64][half*128..+128] -> LDS, coalesced
    {
      const float4* __restrict__ xsrc = reinterpret_cast<const float4*>(
          x + ((size_t)(b * N_ + n0)) * D_ + half * 128);
#pragma unroll
      for (int k = 0; k < 8; ++k) {
        const int idx = t + k * 256;  // 0..2047
        const int sn = idx >> 5;      // local n
        const int sq = idx & 31;      // float4 within 128-chunk
        const float4 v = xsrc[(size_t)sn * 64 + sq];
        float* dst = xl + sn * 129 + sq * 4;
        dst[0] = v.x; dst[1] = v.y; dst[2] = v.z; dst[3] = v.w;
      }
    }
    __syncthreads();

    const float4* __restrict__ w4 = reinterpret_cast<const float4*>(wl_s);
#pragma unroll 4
    for (int d4 = 0; d4 < 32; ++d4) {
      const float x0 = xrow[d4 * 4 + 0];
      const float x1 = xrow[d4 * 4 + 1];
      const float x2 = xrow[d4 * 4 + 2];
      const float x3 = xrow[d4 * 4 + 3];
#pragma unroll
      for (int k = 0; k < 4; ++k) {
        // wave-uniform LDS address -> broadcast ds_read_b128
        const float4 w = w4[(lg * 4 + k) * 64 + half * 32 + d4];
        acc[k] += x0 * w.x + x1 * w.y + x2 * w.z + x3 * w.w;
      }
    }
  }

#pragma unroll
  for (int k = 0; k < 4; ++k) {
    const int l = l0 + lg * 4 + k;
    xs[((size_t)(b * L_ + l)) * N_ + n0 + n] = acc[k] * a[l];  // coalesced
  }
}

// Fused dist+softmax. Block = 1024 thr: group g = t>>9 covers l in
// [g*64, g*64+64) for the same TI=8 rows; partials combined via LDS.
// Group 0 finishes rows 0..3, group 1 rows 4..7.
__global__ __launch_bounds__(1024) void dist_softmax_kernel(
    const float* __restrict__ xs, const float* __restrict__ adj,
    const int* __restrict__ box_num, const float* __restrict__ a,
    float* __restrict__ out) {
  const int t = threadIdx.x;
  const int g = t >> 9;    // l-half group
  const int j = t & 511;   // column
  const int i0 = blockIdx.x * TI;
  const int b = blockIdx.y;
  const int bn = box_num[b];
  const float* __restrict__ xs_b = xs + (size_t)b * L_ * N_;

  __shared__ float xi_l[L_ * TI];       // [l][r], 4 KB
  __shared__ float cross[2][512][4];    // 16 KB partial exchange
  __shared__ float red[16][4];
  __shared__ float sa_l[2];
  __shared__ float rmax_s[2][4];
  __shared__ float rsinv_s[2][4];

  // stage xi rows: 1024 elems, 1/thread: (l = t>>3, r = t&7)
  xi_l[t] = xs_b[(t >> 3) * N_ + i0 + (t & 7)];

  // sum(a)
  {
    float sa = (t < L_) ? a[t] : 0.f;
#pragma unroll
    for (int off = 1; off < 64; off <<= 1) sa += __shfl_xor(sa, off);
    if (t == 0) sa_l[0] = sa;
    if (t == 64) sa_l[1] = sa;
  }
  __syncthreads();
  const float sum_a = sa_l[0] + sa_l[1];

  float acc[TI];
#pragma unroll
  for (int r = 0; r < TI; ++r) acc[r] = 0.f;

  const float4* __restrict__ xi4 = reinterpret_cast<const float4*>(xi_l);
  const int l0 = g * 64;
#pragma unroll 4
  for (int l = l0; l < l0 + 64; ++l) {
    const float xj = xs_b[(size_t)l * N_ + j];  // coalesced, L2-resident
    const float4 A = xi4[2 * l];                // broadcast b128
    const float4 Bv = xi4[2 * l + 1];
    acc[0] += fabsf(A.x - xj);
    acc[1] += fabsf(A.y - xj);
    acc[2] += fabsf(A.z - xj);
    acc[3] += fabsf(A.w - xj);
    acc[4] += fabsf(Bv.x - xj);
    acc[5] += fabsf(Bv.y - xj);
    acc[6] += fabsf(Bv.z - xj);
    acc[7] += fabsf(Bv.w - xj);
  }

  // exchange: give the other group the rows it finishes
  {
    float4 c;
    c.x = acc[(1 - g) * 4 + 0];
    c.y = acc[(1 - g) * 4 + 1];
    c.z = acc[(1 - g) * 4 + 2];
    c.w = acc[(1 - g) * 4 + 3];
    *reinterpret_cast<float4*>(&cross[g][j][0]) = c;
  }
  __syncthreads();

  float val[4];
  {
    const float4 c = *reinterpret_cast<const float4*>(&cross[1 - g][j][0]);
    const float oth[4] = {c.x, c.y, c.z, c.w};
    const bool vj = j < bn;
#pragma unroll
    for (int q = 0; q < 4; ++q) {
      const int row = i0 + g * 4 + q;
      const float d = acc[g * 4 + q] + oth[q] -
                      (((row < bn) && vj) ? 0.f : sum_a);  // + mask*sum(a)
      val[q] = d >= 0.f ? d : 0.01f * d;                   // leaky_relu
    }
  }

  const int lane = t & 63;
  const int wid = t >> 6;  // 0..15; waves 0-7 = group 0, 8-15 = group 1

  // ---- row max over this group's 512 j ----
  {
    float wm[4];
#pragma unroll
    for (int q = 0; q < 4; ++q) {
      float m = val[q];
#pragma unroll
      for (int off = 1; off < 64; off <<= 1) m = fmaxf(m, __shfl_xor(m, off));
      wm[q] = m;
    }
    if (lane == 0) {
#pragma unroll
      for (int q = 0; q < 4; ++q) red[wid][q] = wm[q];
    }
  }
  __syncthreads();
  if (t < 8) {
    const int g2 = t >> 2, q = t & 3;
    float m = red[g2 * 8][q];
#pragma unroll
    for (int w = 1; w < 8; ++w) m = fmaxf(m, red[g2 * 8 + w][q]);
    rmax_s[g2][q] = m;
  }
  __syncthreads();

  float e[4];
  const float* __restrict__ adjp =
      adj + ((size_t)(b * N_ + i0 + g * 4)) * N_ + j;
#pragma unroll
  for (int q = 0; q < 4; ++q) {
    e[q] = adjp[(size_t)q * N_] * __expf(val[q] - rmax_s[g][q]);
  }

  // ---- row sum ----
  {
    float ws[4];
#pragma unroll
    for (int q = 0; q < 4; ++q) {
      float s = e[q];
#pragma unroll
      for (int off = 1; off < 64; off <<= 1) s += __shfl_xor(s, off);
      ws[q] = s;
    }
    if (lane == 0) {
#pragma unroll
      for (int q = 0; q < 4; ++q) red[wid][q] = ws[q];
    }
  }
  __syncthreads();
  if (t < 8) {
    const int g2 = t >> 2, q = t & 3;
    float s = red[g2 * 8][q];
#pragma unroll
    for (int w = 1; w < 8; ++w) s += red[g2 * 8 + w][q];
    rsinv_s[g2][q] = 1.0f / s;
  }
  __syncthreads();

  float* __restrict__ op = out + ((size_t)(b * N_ + i0 + g * 4)) * N_ + j;
#pragma unroll
  for (int q = 0; q < 4; ++q) {
    op[(size_t)q * N_] = e[q] * rsinv_s[g][q] + 1e-10f;
  }
}

}  // namespace

extern "C" void kernel_launch(void* const* d_in, const int* in_sizes, int n_in,
                              void* d_out, int out_size, void* d_ws,
                              size_t ws_size, hipStream_t stream) {
  const float* x = (const float*)d_in[0];    // (B,N,D) f32
  const float* adj = (const float*)d_in[1];  // (B,N,N) f32
  const int* box_num = (const int*)d_in[2];  // (B,1) int32
  const float* W = (const float*)d_in[3];    // (L,D) f32
  const float* a = (const float*)d_in[4];    // (L,) f32
  float* out = (float*)d_out;                // (B,N,N) f32
  float* xs = (float*)d_ws;                  // B*L*N floats = 1 MB scratch

  dim3 g1(L_ / 16, N_ / 64, B_);
  proj_kernel<<<g1, 256, 0, stream>>>(x, W, a, xs);

  dim3 g2(N_ / TI, B_);
  dist_softmax_kernel<<<g2, 1024, 0, stream>>>(xs, adj, box_num, a, out);
}

// Round 8
// 27.438 us; speedup vs baseline: 10.1543x; 1.1054x over previous
//
#include <hip/hip_runtime.h>
#include <math.h>

namespace {

constexpr int B_ = 4;
constexpr int N_ = 512;
constexpr int D_ = 256;
constexpr int L_ = 128;
constexpr int TI = 4;  // i-rows per dist block

// xs[b][l][n] = a[l] * sum_d x[b][n][d] * W[l][d]
// 1D grid, XCD-pinned: batch b runs on XCDs {2b, 2b+1} (blockIdx % 8 -> XCD).
// Block: 256 thr = 64 n x 4 l-groups x 4 l. W-tile and x-tile staged in LDS.
__global__ __launch_bounds__(256) void proj_kernel(
    const float* __restrict__ x, const float* __restrict__ W,
    const float* __restrict__ a, float* __restrict__ xs) {
  const int bid = blockIdx.x;       // 0..255
  const int xcd = bid & 7;          // round-robin XCD assignment
  const int b = xcd >> 1;           // batch pinned to XCD pair
  const int tile = ((xcd & 1) << 5) + (bid >> 3);  // 0..63
  const int l0 = (tile >> 3) * 16;
  const int n0 = (tile & 7) * 64;

  const int t = threadIdx.x;

  __shared__ float wl_s[16 * 256];  // 16 KB W tile
  __shared__ float xl[64 * 129];    // 33 KB x half-tile, pad 129 (conflict-free)

  const int n = t & 63;
  const int lg = t >> 6;  // 0..3, wave-uniform
  const float* __restrict__ xrow = xl + n * 129;

  // stage W tile (16 l x 256 d), coalesced float4
  {
    const float4* __restrict__ Wsrc =
        reinterpret_cast<const float4*>(W + (size_t)l0 * D_);
    float4* wdst = reinterpret_cast<float4*>(wl_s);
#pragma unroll
    for (int k = 0; k < 4; ++k) wdst[t + k * 256] = Wsrc[t + k * 256];
  }

  float acc[4] = {0.f, 0.f, 0.f, 0.f};

#pragma unroll
  for (int half = 0; half < 2; ++half) {
    __syncthreads();  // W ready (half 0) / protect x reuse (half 1)
    {
      const float4* __restrict__ xsrc = reinterpret_cast<const float4*>(
          x + ((size_t)(b * N_ + n0)) * D_ + half * 128);
#pragma unroll
      for (int k = 0; k < 8; ++k) {
        const int idx = t + k * 256;  // 0..2047
        const int sn = idx >> 5;      // local n
        const int sq = idx & 31;      // float4 within 128-chunk
        const float4 v = xsrc[(size_t)sn * 64 + sq];
        float* dst = xl + sn * 129 + sq * 4;
        dst[0] = v.x; dst[1] = v.y; dst[2] = v.z; dst[3] = v.w;
      }
    }
    __syncthreads();

    const float4* __restrict__ w4 = reinterpret_cast<const float4*>(wl_s);
#pragma unroll 4
    for (int d4 = 0; d4 < 32; ++d4) {
      const float x0 = xrow[d4 * 4 + 0];
      const float x1 = xrow[d4 * 4 + 1];
      const float x2 = xrow[d4 * 4 + 2];
      const float x3 = xrow[d4 * 4 + 3];
#pragma unroll
      for (int k = 0; k < 4; ++k) {
        const float4 w = w4[(lg * 4 + k) * 64 + half * 32 + d4];  // broadcast
        acc[k] += x0 * w.x + x1 * w.y + x2 * w.z + x3 * w.w;
      }
    }
  }

#pragma unroll
  for (int k = 0; k < 4; ++k) {
    const int l = l0 + lg * 4 + k;
    xs[((size_t)(b * L_ + l)) * N_ + n0 + n] = acc[k] * a[l];  // coalesced
  }
}

// Fused dist+softmax, R2-proven body. 1D grid, XCD-pinned to match proj:
// batch b's xs lives dirty in XCDs {2b,2b+1} L2 -> xj loop reads are L2-local.
__global__ __launch_bounds__(512) void dist_softmax_kernel(
    const float* __restrict__ xs, const float* __restrict__ adj,
    const int* __restrict__ box_num, const float* __restrict__ a,
    float* __restrict__ out) {
  const int bid = blockIdx.x;       // 0..511
  const int xcd = bid & 7;
  const int b = xcd >> 1;
  const int tile = ((xcd & 1) << 6) + (bid >> 3);  // 0..127
  const int i0 = tile * TI;

  const int t = threadIdx.x;
  const int j = t;
  const int bn = box_num[b];
  const float* __restrict__ xs_b = xs + (size_t)b * L_ * N_;

  __shared__ float xi_l[L_ * TI];  // [l][r], 2 KB, broadcast float4 reads
  __shared__ float red[8][TI];
  __shared__ float sa_l[2];
  __shared__ float rmax_s[TI];
  __shared__ float rsinv_s[TI];

  // stage i-rows: thread t -> (l = t>>2, r = t&3)
  xi_l[t] = xs_b[(t >> 2) * N_ + i0 + (t & 3)];

  // sum(a) prologue
  {
    float sa = (t < L_) ? a[t] : 0.f;
#pragma unroll
    for (int off = 1; off < 64; off <<= 1) sa += __shfl_xor(sa, off);
    if (t == 0) sa_l[0] = sa;
    if (t == 64) sa_l[1] = sa;
  }
  __syncthreads();
  const float sum_a = sa_l[0] + sa_l[1];

  float acc[TI];
#pragma unroll
  for (int r = 0; r < TI; ++r) acc[r] = 0.f;

  const float* __restrict__ pj = xs_b + j;
  const float4* __restrict__ xi4 = reinterpret_cast<const float4*>(xi_l);
#pragma unroll 8
  for (int l = 0; l < L_; ++l) {
    const float xj = pj[(size_t)l * N_];  // coalesced, L2-local after pinning
    const float4 xi = xi4[l];             // broadcast ds_read_b128
    acc[0] += fabsf(xi.x - xj);
    acc[1] += fabsf(xi.y - xj);
    acc[2] += fabsf(xi.z - xj);
    acc[3] += fabsf(xi.w - xj);
  }

  const bool vj = j < bn;
  float val[TI];
#pragma unroll
  for (int r = 0; r < TI; ++r) {
    const bool vi = (i0 + r) < bn;
    const float d = acc[r] - ((vi && vj) ? 0.f : sum_a);  // + mask*sum(a)
    val[r] = d >= 0.f ? d : 0.01f * d;                    // leaky_relu
  }

  const int lane = t & 63;
  const int wid = t >> 6;

  // ---- row max over 512 j ----
  {
    float wm[TI];
#pragma unroll
    for (int r = 0; r < TI; ++r) {
      float m = val[r];
#pragma unroll
      for (int off = 1; off < 64; off <<= 1) m = fmaxf(m, __shfl_xor(m, off));
      wm[r] = m;
    }
    if (lane == 0) {
#pragma unroll
      for (int r = 0; r < TI; ++r) red[wid][r] = wm[r];
    }
  }
  __syncthreads();
  if (t < TI) {
    float m = red[0][t];
#pragma unroll
    for (int w = 1; w < 8; ++w) m = fmaxf(m, red[w][t]);
    rmax_s[t] = m;
  }
  __syncthreads();

  float e[TI];
  const float* __restrict__ adjp = adj + ((size_t)(b * N_ + i0)) * N_ + j;
#pragma unroll
  for (int r = 0; r < TI; ++r) {
    e[r] = adjp[(size_t)r * N_] * __expf(val[r] - rmax_s[r]);
  }

  // ---- row sum over 512 j ----
  {
    float wsum[TI];
#pragma unroll
    for (int r = 0; r < TI; ++r) {
      float s = e[r];
#pragma unroll
      for (int off = 1; off < 64; off <<= 1) s += __shfl_xor(s, off);
      wsum[r] = s;
    }
    if (lane == 0) {
#pragma unroll
      for (int r = 0; r < TI; ++r) red[wid][r] = wsum[r];
    }
  }
  __syncthreads();
  if (t < TI) {
    float s = red[0][t];
#pragma unroll
    for (int w = 1; w < 8; ++w) s += red[w][t];
    rsinv_s[t] = 1.0f / s;
  }
  __syncthreads();

  float* __restrict__ op = out + ((size_t)(b * N_ + i0)) * N_ + j;
#pragma unroll
  for (int r = 0; r < TI; ++r) {
    op[(size_t)r * N_] = e[r] * rsinv_s[r] + 1e-10f;
  }
}

}  // namespace

extern "C" void kernel_launch(void* const* d_in, const int* in_sizes, int n_in,
                              void* d_out, int out_size, void* d_ws,
                              size_t ws_size, hipStream_t stream) {
  const float* x = (const float*)d_in[0];    // (B,N,D) f32
  const float* adj = (const float*)d_in[1];  // (B,N,N) f32
  const int* box_num = (const int*)d_in[2];  // (B,1) int32
  const float* W = (const float*)d_in[3];    // (L,D) f32
  const float* a = (const float*)d_in[4];    // (L,) f32
  float* out = (float*)d_out;                // (B,N,N) f32
  float* xs = (float*)d_ws;                  // B*L*N floats = 1 MB scratch

  proj_kernel<<<256, 256, 0, stream>>>(x, W, a, xs);
  dist_softmax_kernel<<<512, 512, 0, stream>>>(xs, adj, box_num, a, out);
}